// Round 1
// baseline (103.709 us; speedup 1.0000x reference)
//
#include <hip/hip_runtime.h>

// Problem constants (fixed by setup_inputs: 64 graphs x 32 nodes)
constexpr int N_NODES = 2048;
constexpr int G       = 64;
constexpr int D       = 512;
constexpr int H       = 8;
constexpr int HD      = 64;
constexpr int E       = 16;
constexpr int M_EDGES = 16384;

// ---------------------------------------------------------------------------
// 64x64-tile fp32 GEMM with bias: C[M,N] = A[M,K] @ B[K,N] + bias[N]
// block = 256 threads, each computes 4x4 outputs. BK = 16.
// ---------------------------------------------------------------------------
__device__ __forceinline__ void gemm64_body(
    const float* __restrict__ A, const float* __restrict__ B,
    const float* __restrict__ bias, float* __restrict__ C,
    int Mdim, int Ndim, int Kdim)
{
    __shared__ float As[16][68];   // [k][m], stride 68: 16B-aligned rows, low conflicts
    __shared__ float Bs[16][68];   // [k][n]

    const int t  = threadIdx.x;       // 0..255
    const int tx = t & 15;
    const int ty = t >> 4;
    const int row0 = blockIdx.y * 64;
    const int col0 = blockIdx.x * 64;

    float acc[4][4] = {};

    for (int k0 = 0; k0 < Kdim; k0 += 16) {
        // global loads (float4 per thread for each tile)
        float4 av = *(const float4*)(A + (size_t)(row0 + (t >> 2)) * Kdim + k0 + (t & 3) * 4);
        float4 bv = *(const float4*)(B + (size_t)(k0 + (t >> 4)) * Ndim + col0 + (t & 15) * 4);

        __syncthreads();   // previous tile fully consumed
        As[(t & 3) * 4 + 0][t >> 2] = av.x;
        As[(t & 3) * 4 + 1][t >> 2] = av.y;
        As[(t & 3) * 4 + 2][t >> 2] = av.z;
        As[(t & 3) * 4 + 3][t >> 2] = av.w;
        Bs[t >> 4][(t & 15) * 4 + 0] = bv.x;
        Bs[t >> 4][(t & 15) * 4 + 1] = bv.y;
        Bs[t >> 4][(t & 15) * 4 + 2] = bv.z;
        Bs[t >> 4][(t & 15) * 4 + 3] = bv.w;
        __syncthreads();

#pragma unroll
        for (int k = 0; k < 16; ++k) {
            float a0 = As[k][ty * 4 + 0];
            float a1 = As[k][ty * 4 + 1];
            float a2 = As[k][ty * 4 + 2];
            float a3 = As[k][ty * 4 + 3];
            float b0 = Bs[k][tx * 4 + 0];
            float b1 = Bs[k][tx * 4 + 1];
            float b2 = Bs[k][tx * 4 + 2];
            float b3 = Bs[k][tx * 4 + 3];
            acc[0][0] += a0 * b0; acc[0][1] += a0 * b1; acc[0][2] += a0 * b2; acc[0][3] += a0 * b3;
            acc[1][0] += a1 * b0; acc[1][1] += a1 * b1; acc[1][2] += a1 * b2; acc[1][3] += a1 * b3;
            acc[2][0] += a2 * b0; acc[2][1] += a2 * b1; acc[2][2] += a2 * b2; acc[2][3] += a2 * b3;
            acc[3][0] += a3 * b0; acc[3][1] += a3 * b1; acc[3][2] += a3 * b2; acc[3][3] += a3 * b3;
        }
    }

    const float b0 = bias[col0 + tx * 4 + 0];
    const float b1 = bias[col0 + tx * 4 + 1];
    const float b2 = bias[col0 + tx * 4 + 2];
    const float b3 = bias[col0 + tx * 4 + 3];
#pragma unroll
    for (int i = 0; i < 4; ++i) {
        float4 o;
        o.x = acc[i][0] + b0;
        o.y = acc[i][1] + b1;
        o.z = acc[i][2] + b2;
        o.w = acc[i][3] + b3;
        *(float4*)(C + (size_t)(row0 + ty * 4 + i) * Ndim + col0 + tx * 4) = o;
    }
}

__global__ __launch_bounds__(256) void qkv_kernel(
    const float* __restrict__ nodes,
    const float* __restrict__ Wq, const float* __restrict__ bq,
    const float* __restrict__ Wk, const float* __restrict__ bk,
    const float* __restrict__ Wv, const float* __restrict__ bv,
    float* __restrict__ Q, float* __restrict__ K, float* __restrict__ V)
{
    const float* B; const float* bi; float* C;
    if (blockIdx.z == 0)      { B = Wq; bi = bq; C = Q; }
    else if (blockIdx.z == 1) { B = Wk; bi = bk; C = K; }
    else                      { B = Wv; bi = bv; C = V; }
    gemm64_body(nodes, B, bi, C, N_NODES, D, D);
}

__global__ __launch_bounds__(256) void out_kernel(
    const float* __restrict__ AO, const float* __restrict__ Wo,
    const float* __restrict__ bo, float* __restrict__ out)
{
    gemm64_body(AO, Wo, bo, out, N_NODES, D, D);
}

// ---------------------------------------------------------------------------
// Edge bias: two-pass exact ".set" (last edge index wins) into [G][H][32][32]
// ---------------------------------------------------------------------------
__global__ __launch_bounds__(256) void edge_winner_kernel(
    const int* __restrict__ snd, const int* __restrict__ rcv,
    int* __restrict__ winner)
{
    int m = blockIdx.x * 256 + threadIdx.x;
    int s = snd[m], r = rcv[m];
    if ((s >> 5) != (r >> 5)) return;           // cross-graph: masked to -1e9 anyway
    int cell = ((r >> 5) << 10) + ((r & 31) << 5) + (s & 31);
    atomicMax(&winner[cell], m);
}

__global__ __launch_bounds__(256) void edge_scatter_kernel(
    const float* __restrict__ edges, const float* __restrict__ We,
    const float* __restrict__ be,
    const int* __restrict__ snd, const int* __restrict__ rcv,
    const int* __restrict__ winner, float* __restrict__ bias)
{
    int m = blockIdx.x * 256 + threadIdx.x;
    int s = snd[m], r = rcv[m];
    if ((s >> 5) != (r >> 5)) return;
    int g = r >> 5;
    int cell = (g << 10) + ((r & 31) << 5) + (s & 31);
    if (winner[cell] != m) return;              // exact .set semantics: last write wins
    float ef[E];
#pragma unroll
    for (int e = 0; e < E; ++e) ef[e] = edges[m * E + e];
#pragma unroll
    for (int hh = 0; hh < H; ++hh) {
        float v = be[hh];
#pragma unroll
        for (int e = 0; e < E; ++e) v += ef[e] * We[e * H + hh];
        bias[(size_t)((g * H + hh) << 10) + ((r & 31) << 5) + (s & 31)] = v;
    }
}

// ---------------------------------------------------------------------------
// Per-(graph, head) block-diagonal attention.
// block = 1024 threads: thread (i,j) owns score cell [i][j] of the 32x32 tile.
// Masked (cross-graph) keys contribute exactly 0 after softmax -> skipped.
// ---------------------------------------------------------------------------
__global__ __launch_bounds__(1024) void attn_kernel(
    const float* __restrict__ Q, const float* __restrict__ K,
    const float* __restrict__ V, const float* __restrict__ bias,
    float* __restrict__ AO)
{
    const int g = blockIdx.x;
    const int h = blockIdx.y;
    __shared__ float Qs[32][64];
    __shared__ float Ks[32][65];   // +1 pad: conflict-free strided row reads
    __shared__ float Vs[32][65];
    __shared__ float P[32][33];

    const int tid = threadIdx.x;
    for (int idx = tid; idx < 32 * 64; idx += 1024) {
        int n = idx >> 6, d = idx & 63;
        size_t ga = (size_t)(g * 32 + n) * D + h * HD + d;
        Qs[n][d] = Q[ga];
        Ks[n][d] = K[ga];
        Vs[n][d] = V[ga];
    }
    __syncthreads();

    const int i = tid >> 5;        // query row
    const int j = tid & 31;        // key col
    float s = 0.f;
#pragma unroll
    for (int d = 0; d < 64; ++d) s += Qs[i][d] * Ks[j][d];
    s = s * 0.125f + bias[(size_t)((g * H + h) << 10) + (i << 5) + j];

    // softmax across the 32 j-lanes (xor masks < 32 stay within the half-wave)
    float mx = s;
#pragma unroll
    for (int o = 16; o > 0; o >>= 1) mx = fmaxf(mx, __shfl_xor(mx, o));
    float p = __expf(s - mx);
    float sum = p;
#pragma unroll
    for (int o = 16; o > 0; o >>= 1) sum += __shfl_xor(sum, o);
    p /= sum;
    P[i][j] = p;
    __syncthreads();

    // out[i][d] for d = j and j+32
    float o0 = 0.f, o1 = 0.f;
#pragma unroll
    for (int kk = 0; kk < 32; ++kk) {
        float pv = P[i][kk];
        o0 += pv * Vs[kk][j];
        o1 += pv * Vs[kk][j + 32];
    }
    size_t oa = (size_t)(g * 32 + i) * D + h * HD;
    AO[oa + j]      = o0;
    AO[oa + j + 32] = o1;
}

// ---------------------------------------------------------------------------
extern "C" void kernel_launch(void* const* d_in, const int* in_sizes, int n_in,
                              void* d_out, int out_size, void* d_ws, size_t ws_size,
                              hipStream_t stream)
{
    const float* nodes = (const float*)d_in[0];
    const float* edges = (const float*)d_in[1];
    const float* Wq    = (const float*)d_in[2];
    const float* bq    = (const float*)d_in[3];
    const float* Wk    = (const float*)d_in[4];
    const float* bk    = (const float*)d_in[5];
    const float* Wv    = (const float*)d_in[6];
    const float* bv    = (const float*)d_in[7];
    const float* Wo    = (const float*)d_in[8];
    const float* bo    = (const float*)d_in[9];
    const float* We    = (const float*)d_in[10];
    const float* be    = (const float*)d_in[11];
    // d_in[12] = n_node (fixed: 64 graphs x 32 contiguous nodes)
    const int* senders   = (const int*)d_in[13];
    const int* receivers = (const int*)d_in[14];

    float* ws   = (float*)d_ws;
    float* Qb   = ws;
    float* Kb   = Qb + (size_t)N_NODES * D;
    float* Vb   = Kb + (size_t)N_NODES * D;
    float* AO   = Vb + (size_t)N_NODES * D;
    float* bias = AO + (size_t)N_NODES * D;            // [G][H][32][32]
    int*   winner = (int*)(bias + (size_t)G * H * 1024); // [G][32][32]

    hipMemsetAsync(winner, 0xFF, (size_t)G * 1024 * sizeof(int), stream);  // -1
    hipMemsetAsync(bias, 0, (size_t)G * H * 1024 * sizeof(float), stream);

    dim3 gqkv(D / 64, N_NODES / 64, 3);
    qkv_kernel<<<gqkv, 256, 0, stream>>>(nodes, Wq, bq, Wk, bk, Wv, bv, Qb, Kb, Vb);

    edge_winner_kernel<<<M_EDGES / 256, 256, 0, stream>>>(senders, receivers, winner);
    edge_scatter_kernel<<<M_EDGES / 256, 256, 0, stream>>>(edges, We, be, senders,
                                                           receivers, winner, bias);

    attn_kernel<<<dim3(G, H), 1024, 0, stream>>>(Qb, Kb, Vb, bias, AO);

    out_kernel<<<dim3(D / 64, N_NODES / 64), 256, 0, stream>>>(AO, Wo, bo, (float*)d_out);
}

// Round 2
// 93.620 us; speedup vs baseline: 1.1078x; 1.1078x over previous
//
#include <hip/hip_runtime.h>

// Problem constants (fixed by setup_inputs: 64 graphs x 32 nodes)
constexpr int N_NODES = 2048;
constexpr int G       = 64;
constexpr int D       = 512;
constexpr int H       = 8;
constexpr int HD      = 64;
constexpr int E       = 16;
constexpr int M_EDGES = 16384;

typedef __attribute__((ext_vector_type(8))) short bf16x8;
typedef __attribute__((ext_vector_type(4))) float f32x4;

// ---------------------------------------------------------------------------
// bf16 helpers (round-to-nearest-even)
// ---------------------------------------------------------------------------
__device__ __forceinline__ unsigned short f2bf(float f) {
    union { float f; unsigned u; } v; v.f = f;
    unsigned r = v.u + 0x7fff + ((v.u >> 16) & 1);
    return (unsigned short)(r >> 16);
}
__device__ __forceinline__ float bf2f(unsigned short b) {
    union { unsigned u; float f; } v; v.u = ((unsigned)b) << 16; return v.f;
}

__device__ __forceinline__ void load_lds16(const void* g, void* l) {
    __builtin_amdgcn_global_load_lds(
        (const __attribute__((address_space(1))) unsigned int*)g,
        (__attribute__((address_space(3))) unsigned int*)l, 16, 0, 0);
}

// ---------------------------------------------------------------------------
// Split fp32 -> bf16 hi/lo (elementwise), 8 elems/thread
// ---------------------------------------------------------------------------
__global__ __launch_bounds__(256) void split_a_kernel(
    const float* __restrict__ A, unsigned short* __restrict__ hi,
    unsigned short* __restrict__ lo, int n8)
{
    int i = blockIdx.x * 256 + threadIdx.x;
    if (i >= n8) return;
    float4 v0 = ((const float4*)A)[2 * i];
    float4 v1 = ((const float4*)A)[2 * i + 1];
    float f[8] = { v0.x, v0.y, v0.z, v0.w, v1.x, v1.y, v1.z, v1.w };
    union { unsigned short u[8]; int4 v; } ph, pl;
#pragma unroll
    for (int e = 0; e < 8; ++e) {
        unsigned short h = f2bf(f[e]);
        ph.u[e] = h;
        pl.u[e] = f2bf(f[e] - bf2f(h));
    }
    ((int4*)hi)[i] = ph.v;
    ((int4*)lo)[i] = pl.v;
}

// ---------------------------------------------------------------------------
// Split + transpose the 4 weight matrices: WtT[z][n][k] = W_z[k][n], bf16 hi/lo
// grid (16,16,4), 256 threads, 32x32 tiles
// ---------------------------------------------------------------------------
__global__ __launch_bounds__(256) void split_wT_kernel(
    const float* __restrict__ Wq, const float* __restrict__ Wk,
    const float* __restrict__ Wv, const float* __restrict__ Wo,
    unsigned short* __restrict__ hiT, unsigned short* __restrict__ loT)
{
    const int z = blockIdx.z;
    const float* W = (z == 0) ? Wq : (z == 1) ? Wk : (z == 2) ? Wv : Wo;
    __shared__ float tile[32][33];   // [n][k]
    const int tid = threadIdx.x;
    const int k0 = blockIdx.y * 32, n0 = blockIdx.x * 32;

    {   // load W[k0+kr][n0 + nc4 .. +3]
        int kr = tid >> 3, nc4 = (tid & 7) * 4;
        float4 v = *(const float4*)(W + (size_t)(k0 + kr) * D + n0 + nc4);
        tile[nc4 + 0][kr] = v.x;
        tile[nc4 + 1][kr] = v.y;
        tile[nc4 + 2][kr] = v.z;
        tile[nc4 + 3][kr] = v.w;
    }
    __syncthreads();
    {   // write WtT[n0+nl][k0 + kq .. +3]
        int nl = tid >> 3, kq = (tid & 7) * 4;
        union { unsigned short u[4]; ushort4 v; } h, l;
#pragma unroll
        for (int j = 0; j < 4; ++j) {
            float f = tile[nl][kq + j];
            unsigned short hb = f2bf(f);
            h.u[j] = hb;
            l.u[j] = f2bf(f - bf2f(hb));
        }
        size_t base = (size_t)z * D * D + (size_t)(n0 + nl) * D + k0 + kq;
        *(ushort4*)(hiT + base) = h.v;
        *(ushort4*)(loT + base) = l.v;
    }
}

// ---------------------------------------------------------------------------
// Split-bf16 MFMA GEMM: C[M=2048, N=512] fp32 =
//    Ahi@BhiT' + Ahi@BloT' + Alo@BhiT'  (+ bias)
// B given TRANSPOSED: BT[n][k]. Tile BM=128, BN=64, BK=32; 256 thr = 4 waves.
// LDS double-buffered; global_load_lds width 16 with pre-swizzled source;
// ds_read_b128 with slot ^= (row&3) swizzle (<=4-way conflicts).
// ---------------------------------------------------------------------------
struct GemmArgs {
    const unsigned short *Ahi, *Alo, *BhiT, *BloT;
    const float* bias[3];
    float* C;
};

__global__ __launch_bounds__(256) void gemm_split_kernel(GemmArgs a)
{
    const int z = blockIdx.z;
    const unsigned short* Ahi = a.Ahi;
    const unsigned short* Alo = a.Alo;
    const unsigned short* Bhi = a.BhiT + (size_t)z * D * D;
    const unsigned short* Blo = a.BloT + (size_t)z * D * D;
    const float* bias = a.bias[z];
    float* C = a.C + (size_t)z * N_NODES * D;

    __shared__ __align__(16) unsigned short As[2][128 * 32];  // 8 KB each
    __shared__ __align__(16) unsigned short Bs[2][64 * 32];   // 4 KB each

    const int t    = threadIdx.x;
    const int lane = t & 63;
    const int w    = t >> 6;
    const int wm   = w >> 1, wn = w & 1;       // wave grid 2x2 over 128x64
    const int row0 = blockIdx.y * 128;
    const int col0 = blockIdx.x * 64;

    // staging: physical LDS bytes F = issue*4096 + t*16 -> cell(prow=F>>6, pslot)
    // logical slot = pslot ^ (prow&3); global src pre-swizzled accordingly.
    const int aF0 = t * 16,        ar0 = aF0 >> 6, as0 = ((aF0 >> 4) & 3) ^ (ar0 & 3);
    const int aF1 = 4096 + t * 16, ar1 = aF1 >> 6, as1 = ((aF1 >> 4) & 3) ^ (ar1 & 3);
    const int br  = (t * 16) >> 6, bs  = (((t * 16) >> 4) & 3) ^ (br & 3);

    auto stage = [&](int buf, const unsigned short* Aseg, const unsigned short* Bseg, int k0) {
        const char* gA0 = (const char*)Aseg + (size_t)(row0 + ar0) * 1024 + k0 * 2 + as0 * 16;
        const char* gA1 = (const char*)Aseg + (size_t)(row0 + ar1) * 1024 + k0 * 2 + as1 * 16;
        const char* gB  = (const char*)Bseg + (size_t)(col0 + br)  * 1024 + k0 * 2 + bs  * 16;
        char* lA0 = (char*)&As[buf][0] + (w << 10);
        char* lA1 = (char*)&As[buf][0] + 4096 + (w << 10);
        char* lB  = (char*)&Bs[buf][0] + (w << 10);
        load_lds16(gA0, lA0);
        load_lds16(gA1, lA1);
        load_lds16(gB, lB);
    };

    f32x4 acc[4][2] = {};

    stage(0, Ahi, Bhi, 0);
    __syncthreads();

    int cur = 0;
    for (int tstep = 0; tstep < 48; ++tstep) {
        int nxt = tstep + 1;
        if (nxt < 48) {
            const unsigned short* An; const unsigned short* Bn;
            int sg = nxt >> 4;
            if (sg == 0)      { An = Ahi; Bn = Bhi; }
            else if (sg == 1) { An = Ahi; Bn = Blo; }
            else              { An = Alo; Bn = Bhi; }
            stage(cur ^ 1, An, Bn, (nxt & 15) * 32);
        }

        bf16x8 af[4], bfr[2];
#pragma unroll
        for (int mf = 0; mf < 4; ++mf) {
            int row  = wm * 64 + mf * 16 + (lane & 15);
            int slot = (lane >> 4) ^ (row & 3);
            af[mf] = *(const bf16x8*)((const char*)&As[cur][0] + row * 64 + slot * 16);
        }
#pragma unroll
        for (int nf = 0; nf < 2; ++nf) {
            int row  = wn * 32 + nf * 16 + (lane & 15);
            int slot = (lane >> 4) ^ (row & 3);
            bfr[nf] = *(const bf16x8*)((const char*)&Bs[cur][0] + row * 64 + slot * 16);
        }
#pragma unroll
        for (int mf = 0; mf < 4; ++mf)
#pragma unroll
            for (int nf = 0; nf < 2; ++nf)
                acc[mf][nf] = __builtin_amdgcn_mfma_f32_16x16x32_bf16(
                    af[mf], bfr[nf], acc[mf][nf], 0, 0, 0);

        __syncthreads();
        cur ^= 1;
    }

    // epilogue: C/D layout col=lane&15, row=(lane>>4)*4+reg
#pragma unroll
    for (int mf = 0; mf < 4; ++mf)
#pragma unroll
        for (int nf = 0; nf < 2; ++nf) {
            int col = col0 + wn * 32 + nf * 16 + (lane & 15);
            float bv = bias[col];
#pragma unroll
            for (int r = 0; r < 4; ++r) {
                int row = row0 + wm * 64 + mf * 16 + (lane >> 4) * 4 + r;
                C[(size_t)row * D + col] = acc[mf][nf][r] + bv;
            }
        }
}

// ---------------------------------------------------------------------------
// Edge bias: two-pass exact ".set" (last edge index wins) into [G][H][32][32]
// ---------------------------------------------------------------------------
__global__ __launch_bounds__(256) void edge_winner_kernel(
    const int* __restrict__ snd, const int* __restrict__ rcv,
    int* __restrict__ winner)
{
    int m = blockIdx.x * 256 + threadIdx.x;
    int s = snd[m], r = rcv[m];
    if ((s >> 5) != (r >> 5)) return;
    int cell = ((r >> 5) << 10) + ((r & 31) << 5) + (s & 31);
    atomicMax(&winner[cell], m);
}

__global__ __launch_bounds__(256) void edge_scatter_kernel(
    const float* __restrict__ edges, const float* __restrict__ We,
    const float* __restrict__ be,
    const int* __restrict__ snd, const int* __restrict__ rcv,
    const int* __restrict__ winner, float* __restrict__ bias)
{
    int m = blockIdx.x * 256 + threadIdx.x;
    int s = snd[m], r = rcv[m];
    if ((s >> 5) != (r >> 5)) return;
    int g = r >> 5;
    int cell = (g << 10) + ((r & 31) << 5) + (s & 31);
    if (winner[cell] != m) return;
    float ef[E];
#pragma unroll
    for (int e = 0; e < E; ++e) ef[e] = edges[m * E + e];
#pragma unroll
    for (int hh = 0; hh < H; ++hh) {
        float v = be[hh];
#pragma unroll
        for (int e = 0; e < E; ++e) v += ef[e] * We[e * H + hh];
        bias[(size_t)((g * H + hh) << 10) + ((r & 31) << 5) + (s & 31)] = v;
    }
}

// ---------------------------------------------------------------------------
// Per-(graph, head) block-diagonal attention; writes output pre-split bf16.
// ---------------------------------------------------------------------------
__global__ __launch_bounds__(1024) void attn_kernel(
    const float* __restrict__ Q, const float* __restrict__ K,
    const float* __restrict__ V, const float* __restrict__ bias,
    unsigned short* __restrict__ AOhi, unsigned short* __restrict__ AOlo)
{
    const int g = blockIdx.x;
    const int h = blockIdx.y;
    __shared__ float Qs[32][64];
    __shared__ float Ks[32][65];
    __shared__ float Vs[32][65];
    __shared__ float P[32][33];

    const int tid = threadIdx.x;
    for (int idx = tid; idx < 32 * 64; idx += 1024) {
        int n = idx >> 6, d = idx & 63;
        size_t ga = (size_t)(g * 32 + n) * D + h * HD + d;
        Qs[n][d] = Q[ga];
        Ks[n][d] = K[ga];
        Vs[n][d] = V[ga];
    }
    __syncthreads();

    const int i = tid >> 5;
    const int j = tid & 31;
    float s = 0.f;
#pragma unroll
    for (int d = 0; d < 64; ++d) s += Qs[i][d] * Ks[j][d];
    s = s * 0.125f + bias[(size_t)((g * H + h) << 10) + (i << 5) + j];

    float mx = s;
#pragma unroll
    for (int o = 16; o > 0; o >>= 1) mx = fmaxf(mx, __shfl_xor(mx, o));
    float p = __expf(s - mx);
    float sum = p;
#pragma unroll
    for (int o = 16; o > 0; o >>= 1) sum += __shfl_xor(sum, o);
    p /= sum;
    P[i][j] = p;
    __syncthreads();

    float o0 = 0.f, o1 = 0.f;
#pragma unroll
    for (int kk = 0; kk < 32; ++kk) {
        float pv = P[i][kk];
        o0 += pv * Vs[kk][j];
        o1 += pv * Vs[kk][j + 32];
    }
    size_t oa = (size_t)(g * 32 + i) * D + h * HD;
    unsigned short h0 = f2bf(o0);
    unsigned short h1 = f2bf(o1);
    AOhi[oa + j]      = h0;
    AOlo[oa + j]      = f2bf(o0 - bf2f(h0));
    AOhi[oa + j + 32] = h1;
    AOlo[oa + j + 32] = f2bf(o1 - bf2f(h1));
}

// ---------------------------------------------------------------------------
extern "C" void kernel_launch(void* const* d_in, const int* in_sizes, int n_in,
                              void* d_out, int out_size, void* d_ws, size_t ws_size,
                              hipStream_t stream)
{
    const float* nodes = (const float*)d_in[0];
    const float* edges = (const float*)d_in[1];
    const float* Wq    = (const float*)d_in[2];
    const float* bq    = (const float*)d_in[3];
    const float* Wk    = (const float*)d_in[4];
    const float* bk    = (const float*)d_in[5];
    const float* Wv    = (const float*)d_in[6];
    const float* bv    = (const float*)d_in[7];
    const float* Wo    = (const float*)d_in[8];
    const float* bo    = (const float*)d_in[9];
    const float* We    = (const float*)d_in[10];
    const float* be    = (const float*)d_in[11];
    const int* senders   = (const int*)d_in[13];
    const int* receivers = (const int*)d_in[14];

    // workspace layout (bytes)
    char* ws = (char*)d_ws;
    float* Qb    = (float*)ws;                                   // 4 MB
    float* Kb    = Qb + (size_t)N_NODES * D;                     // 4 MB
    float* Vb    = Kb + (size_t)N_NODES * D;                     // 4 MB
    float* biasA = Vb + (size_t)N_NODES * D;                     // 2 MB
    int*   winner = (int*)(biasA + (size_t)G * H * 1024);        // 256 KB
    unsigned short* nAhi = (unsigned short*)(winner + G * 1024); // 2 MB
    unsigned short* nAlo = nAhi + (size_t)N_NODES * D;           // 2 MB
    unsigned short* wThi = nAlo + (size_t)N_NODES * D;           // 2 MB (4x512x512)
    unsigned short* wTlo = wThi + (size_t)4 * D * D;             // 2 MB
    unsigned short* AOhi = wTlo + (size_t)4 * D * D;             // 2 MB
    unsigned short* AOlo = AOhi + (size_t)N_NODES * D;           // 2 MB

    hipMemsetAsync(winner, 0xFF, (size_t)G * 1024 * sizeof(int), stream);
    hipMemsetAsync(biasA, 0, (size_t)G * H * 1024 * sizeof(float), stream);

    split_a_kernel<<<(N_NODES * D / 8 + 255) / 256, 256, 0, stream>>>(
        nodes, nAhi, nAlo, N_NODES * D / 8);
    split_wT_kernel<<<dim3(16, 16, 4), 256, 0, stream>>>(Wq, Wk, Wv, Wo, wThi, wTlo);

    // QKV: one dispatch, z = 0/1/2 selects weights & bias & output
    GemmArgs qkv;
    qkv.Ahi = nAhi; qkv.Alo = nAlo;
    qkv.BhiT = wThi; qkv.BloT = wTlo;
    qkv.bias[0] = bq; qkv.bias[1] = bk; qkv.bias[2] = bv;
    qkv.C = Qb;   // Qb,Kb,Vb contiguous
    gemm_split_kernel<<<dim3(D / 64, N_NODES / 128, 3), 256, 0, stream>>>(qkv);

    edge_winner_kernel<<<M_EDGES / 256, 256, 0, stream>>>(senders, receivers, winner);
    edge_scatter_kernel<<<M_EDGES / 256, 256, 0, stream>>>(edges, We, be, senders,
                                                           receivers, winner, biasA);

    attn_kernel<<<dim3(G, H), 1024, 0, stream>>>(Qb, Kb, Vb, biasA, AOhi, AOlo);

    // output GEMM: z=0, weights at slot 3 (Wo)
    GemmArgs og;
    og.Ahi = AOhi; og.Alo = AOlo;
    og.BhiT = wThi + (size_t)3 * D * D; og.BloT = wTlo + (size_t)3 * D * D;
    og.bias[0] = bo; og.bias[1] = bo; og.bias[2] = bo;
    og.C = (float*)d_out;
    gemm_split_kernel<<<dim3(D / 64, N_NODES / 128, 1), 256, 0, stream>>>(og);
}

// Round 3
// 89.051 us; speedup vs baseline: 1.1646x; 1.0513x over previous
//
#include <hip/hip_runtime.h>

// Problem constants (fixed by setup_inputs: 64 graphs x 32 nodes)
constexpr int N_NODES = 2048;
constexpr int G       = 64;
constexpr int D       = 512;
constexpr int H       = 8;
constexpr int HD      = 64;
constexpr int E       = 16;
constexpr int M_EDGES = 16384;

typedef __attribute__((ext_vector_type(8))) short bf16x8;
typedef __attribute__((ext_vector_type(4))) float f32x4;

// ---------------------------------------------------------------------------
// bf16 helpers (round-to-nearest-even)
// ---------------------------------------------------------------------------
__device__ __forceinline__ unsigned short f2bf(float f) {
    union { float f; unsigned u; } v; v.f = f;
    unsigned r = v.u + 0x7fff + ((v.u >> 16) & 1);
    return (unsigned short)(r >> 16);
}
__device__ __forceinline__ float bf2f(unsigned short b) {
    union { unsigned u; float f; } v; v.u = ((unsigned)b) << 16; return v.f;
}

__device__ __forceinline__ void load_lds16(const void* g, void* l) {
    __builtin_amdgcn_global_load_lds(
        (const __attribute__((address_space(1))) unsigned int*)g,
        (__attribute__((address_space(3))) unsigned int*)l, 16, 0, 0);
}

// ---------------------------------------------------------------------------
// winner init: 64K ints to -1 (replaces hipMemsetAsync: ~41us graph overhead)
// ---------------------------------------------------------------------------
__global__ __launch_bounds__(256) void init_winner_kernel(int4* __restrict__ w)
{
    w[blockIdx.x * 256 + threadIdx.x] = make_int4(-1, -1, -1, -1);
}

// ---------------------------------------------------------------------------
// Split fp32 -> bf16 hi/lo (elementwise), 8 elems/thread
// ---------------------------------------------------------------------------
__global__ __launch_bounds__(256) void split_a_kernel(
    const float* __restrict__ A, unsigned short* __restrict__ hi,
    unsigned short* __restrict__ lo, int n8)
{
    int i = blockIdx.x * 256 + threadIdx.x;
    if (i >= n8) return;
    float4 v0 = ((const float4*)A)[2 * i];
    float4 v1 = ((const float4*)A)[2 * i + 1];
    float f[8] = { v0.x, v0.y, v0.z, v0.w, v1.x, v1.y, v1.z, v1.w };
    union { unsigned short u[8]; int4 v; } ph, pl;
#pragma unroll
    for (int e = 0; e < 8; ++e) {
        unsigned short h = f2bf(f[e]);
        ph.u[e] = h;
        pl.u[e] = f2bf(f[e] - bf2f(h));
    }
    ((int4*)hi)[i] = ph.v;
    ((int4*)lo)[i] = pl.v;
}

// ---------------------------------------------------------------------------
// Split + transpose the 4 weight matrices: WtT[z][n][k] = W_z[k][n], bf16 hi/lo
// grid (16,16,4), 256 threads, 32x32 tiles
// ---------------------------------------------------------------------------
__global__ __launch_bounds__(256) void split_wT_kernel(
    const float* __restrict__ Wq, const float* __restrict__ Wk,
    const float* __restrict__ Wv, const float* __restrict__ Wo,
    unsigned short* __restrict__ hiT, unsigned short* __restrict__ loT)
{
    const int z = blockIdx.z;
    const float* W = (z == 0) ? Wq : (z == 1) ? Wk : (z == 2) ? Wv : Wo;
    __shared__ float tile[32][33];   // [n][k]
    const int tid = threadIdx.x;
    const int k0 = blockIdx.y * 32, n0 = blockIdx.x * 32;

    {   // load W[k0+kr][n0 + nc4 .. +3]
        int kr = tid >> 3, nc4 = (tid & 7) * 4;
        float4 v = *(const float4*)(W + (size_t)(k0 + kr) * D + n0 + nc4);
        tile[nc4 + 0][kr] = v.x;
        tile[nc4 + 1][kr] = v.y;
        tile[nc4 + 2][kr] = v.z;
        tile[nc4 + 3][kr] = v.w;
    }
    __syncthreads();
    {   // write WtT[n0+nl][k0 + kq .. +3]
        int nl = tid >> 3, kq = (tid & 7) * 4;
        union { unsigned short u[4]; ushort4 v; } h, l;
#pragma unroll
        for (int j = 0; j < 4; ++j) {
            float f = tile[nl][kq + j];
            unsigned short hb = f2bf(f);
            h.u[j] = hb;
            l.u[j] = f2bf(f - bf2f(hb));
        }
        size_t base = (size_t)z * D * D + (size_t)(n0 + nl) * D + k0 + kq;
        *(ushort4*)(hiT + base) = h.v;
        *(ushort4*)(loT + base) = l.v;
    }
}

// ---------------------------------------------------------------------------
// Split-bf16 MFMA GEMM: C[M=2048, N=512] fp32 =
//    Ahi@BhiT' + Ahi@BloT' + Alo@BhiT'  (+ bias)
// B given TRANSPOSED: BT[n][k]. Tile BM=128, BN=64, BK=32; 256 thr = 4 waves.
// LDS double-buffered; global_load_lds width 16 with pre-swizzled source;
// ds_read_b128 with slot ^= (row&3) swizzle (<=4-way conflicts).
// ---------------------------------------------------------------------------
struct GemmArgs {
    const unsigned short *Ahi, *Alo, *BhiT, *BloT;
    const float* bias[3];
    float* C;
};

__global__ __launch_bounds__(256) void gemm_split_kernel(GemmArgs a)
{
    const int z = blockIdx.z;
    const unsigned short* Ahi = a.Ahi;
    const unsigned short* Alo = a.Alo;
    const unsigned short* Bhi = a.BhiT + (size_t)z * D * D;
    const unsigned short* Blo = a.BloT + (size_t)z * D * D;
    const float* bias = a.bias[z];
    float* C = a.C + (size_t)z * N_NODES * D;

    __shared__ __align__(16) unsigned short As[2][128 * 32];  // 8 KB each
    __shared__ __align__(16) unsigned short Bs[2][64 * 32];   // 4 KB each

    const int t    = threadIdx.x;
    const int lane = t & 63;
    const int w    = t >> 6;
    const int wm   = w >> 1, wn = w & 1;       // wave grid 2x2 over 128x64
    const int row0 = blockIdx.y * 128;
    const int col0 = blockIdx.x * 64;

    // staging: physical LDS bytes F = issue*4096 + t*16 -> cell(prow=F>>6, pslot)
    // logical slot = pslot ^ (prow&3); global src pre-swizzled accordingly.
    const int aF0 = t * 16,        ar0 = aF0 >> 6, as0 = ((aF0 >> 4) & 3) ^ (ar0 & 3);
    const int aF1 = 4096 + t * 16, ar1 = aF1 >> 6, as1 = ((aF1 >> 4) & 3) ^ (ar1 & 3);
    const int br  = (t * 16) >> 6, bs  = (((t * 16) >> 4) & 3) ^ (br & 3);

    auto stage = [&](int buf, const unsigned short* Aseg, const unsigned short* Bseg, int k0) {
        const char* gA0 = (const char*)Aseg + (size_t)(row0 + ar0) * 1024 + k0 * 2 + as0 * 16;
        const char* gA1 = (const char*)Aseg + (size_t)(row0 + ar1) * 1024 + k0 * 2 + as1 * 16;
        const char* gB  = (const char*)Bseg + (size_t)(col0 + br)  * 1024 + k0 * 2 + bs  * 16;
        char* lA0 = (char*)&As[buf][0] + (w << 10);
        char* lA1 = (char*)&As[buf][0] + 4096 + (w << 10);
        char* lB  = (char*)&Bs[buf][0] + (w << 10);
        load_lds16(gA0, lA0);
        load_lds16(gA1, lA1);
        load_lds16(gB, lB);
    };

    f32x4 acc[4][2] = {};

    stage(0, Ahi, Bhi, 0);
    __syncthreads();

    int cur = 0;
    for (int tstep = 0; tstep < 48; ++tstep) {
        int nxt = tstep + 1;
        if (nxt < 48) {
            const unsigned short* An; const unsigned short* Bn;
            int sg = nxt >> 4;
            if (sg == 0)      { An = Ahi; Bn = Bhi; }
            else if (sg == 1) { An = Ahi; Bn = Blo; }
            else              { An = Alo; Bn = Bhi; }
            stage(cur ^ 1, An, Bn, (nxt & 15) * 32);
        }

        bf16x8 af[4], bfr[2];
#pragma unroll
        for (int mf = 0; mf < 4; ++mf) {
            int row  = wm * 64 + mf * 16 + (lane & 15);
            int slot = (lane >> 4) ^ (row & 3);
            af[mf] = *(const bf16x8*)((const char*)&As[cur][0] + row * 64 + slot * 16);
        }
#pragma unroll
        for (int nf = 0; nf < 2; ++nf) {
            int row  = wn * 32 + nf * 16 + (lane & 15);
            int slot = (lane >> 4) ^ (row & 3);
            bfr[nf] = *(const bf16x8*)((const char*)&Bs[cur][0] + row * 64 + slot * 16);
        }
#pragma unroll
        for (int mf = 0; mf < 4; ++mf)
#pragma unroll
            for (int nf = 0; nf < 2; ++nf)
                acc[mf][nf] = __builtin_amdgcn_mfma_f32_16x16x32_bf16(
                    af[mf], bfr[nf], acc[mf][nf], 0, 0, 0);

        __syncthreads();
        cur ^= 1;
    }

    // epilogue: C/D layout col=lane&15, row=(lane>>4)*4+reg
#pragma unroll
    for (int mf = 0; mf < 4; ++mf)
#pragma unroll
        for (int nf = 0; nf < 2; ++nf) {
            int col = col0 + wn * 32 + nf * 16 + (lane & 15);
            float bv = bias[col];
#pragma unroll
            for (int r = 0; r < 4; ++r) {
                int row = row0 + wm * 64 + mf * 16 + (lane >> 4) * 4 + r;
                C[(size_t)row * D + col] = acc[mf][nf][r] + bv;
            }
        }
}

// ---------------------------------------------------------------------------
// Edge winner: exact ".set" (last edge index wins) per (receiver, sender) cell
// ---------------------------------------------------------------------------
__global__ __launch_bounds__(256) void edge_winner_kernel(
    const int* __restrict__ snd, const int* __restrict__ rcv,
    int* __restrict__ winner)
{
    int m = blockIdx.x * 256 + threadIdx.x;
    int s = snd[m], r = rcv[m];
    if ((s >> 5) != (r >> 5)) return;           // cross-graph: masked to -1e9 anyway
    int cell = ((r >> 5) << 10) + ((r & 31) << 5) + (s & 31);
    atomicMax(&winner[cell], m);
}

// ---------------------------------------------------------------------------
// Per-(graph, head) block-diagonal attention; edge bias computed inline from
// winner (exact .set semantics); writes output pre-split bf16.
// ---------------------------------------------------------------------------
__global__ __launch_bounds__(1024) void attn_kernel(
    const float* __restrict__ Q, const float* __restrict__ K,
    const float* __restrict__ V,
    const float* __restrict__ edges, const float* __restrict__ We,
    const float* __restrict__ be, const int* __restrict__ winner,
    unsigned short* __restrict__ AOhi, unsigned short* __restrict__ AOlo)
{
    const int g = blockIdx.x;
    const int h = blockIdx.y;
    __shared__ float Qs[32][64];
    __shared__ float Ks[32][65];
    __shared__ float Vs[32][65];
    __shared__ float P[32][33];
    __shared__ float Wes[E];       // We column for this head

    const int tid = threadIdx.x;
    if (tid < E) Wes[tid] = We[tid * H + h];
    for (int idx = tid; idx < 32 * 64; idx += 1024) {
        int n = idx >> 6, d = idx & 63;
        size_t ga = (size_t)(g * 32 + n) * D + h * HD + d;
        Qs[n][d] = Q[ga];
        Ks[n][d] = K[ga];
        Vs[n][d] = V[ga];
    }
    __syncthreads();

    const int i = tid >> 5;        // query row (receiver)
    const int j = tid & 31;        // key col (sender)
    float s = 0.f;
#pragma unroll
    for (int d = 0; d < 64; ++d) s += Qs[i][d] * Ks[j][d];
    s *= 0.125f;

    // inline edge bias (cells without a winning edge get exactly 0)
    int m = winner[(g << 10) + (i << 5) + j];
    if (m >= 0) {
        float v = be[h];
#pragma unroll
        for (int e = 0; e < E; ++e) v += edges[m * E + e] * Wes[e];
        s += v;
    }

    // softmax across the 32 j-lanes (xor masks < 32 stay within the half-wave)
    float mx = s;
#pragma unroll
    for (int o = 16; o > 0; o >>= 1) mx = fmaxf(mx, __shfl_xor(mx, o));
    float p = __expf(s - mx);
    float sum = p;
#pragma unroll
    for (int o = 16; o > 0; o >>= 1) sum += __shfl_xor(sum, o);
    p /= sum;
    P[i][j] = p;
    __syncthreads();

    // out[i][d] for d = j and j+32
    float o0 = 0.f, o1 = 0.f;
#pragma unroll
    for (int kk = 0; kk < 32; ++kk) {
        float pv = P[i][kk];
        o0 += pv * Vs[kk][j];
        o1 += pv * Vs[kk][j + 32];
    }
    size_t oa = (size_t)(g * 32 + i) * D + h * HD;
    unsigned short h0 = f2bf(o0);
    unsigned short h1 = f2bf(o1);
    AOhi[oa + j]      = h0;
    AOlo[oa + j]      = f2bf(o0 - bf2f(h0));
    AOhi[oa + j + 32] = h1;
    AOlo[oa + j + 32] = f2bf(o1 - bf2f(h1));
}

// ---------------------------------------------------------------------------
extern "C" void kernel_launch(void* const* d_in, const int* in_sizes, int n_in,
                              void* d_out, int out_size, void* d_ws, size_t ws_size,
                              hipStream_t stream)
{
    const float* nodes = (const float*)d_in[0];
    const float* edges = (const float*)d_in[1];
    const float* Wq    = (const float*)d_in[2];
    const float* bq    = (const float*)d_in[3];
    const float* Wk    = (const float*)d_in[4];
    const float* bk    = (const float*)d_in[5];
    const float* Wv    = (const float*)d_in[6];
    const float* bv    = (const float*)d_in[7];
    const float* Wo    = (const float*)d_in[8];
    const float* bo    = (const float*)d_in[9];
    const float* We    = (const float*)d_in[10];
    const float* be    = (const float*)d_in[11];
    const int* senders   = (const int*)d_in[13];
    const int* receivers = (const int*)d_in[14];

    // workspace layout
    char* ws = (char*)d_ws;
    float* Qb    = (float*)ws;                                   // 4 MB
    float* Kb    = Qb + (size_t)N_NODES * D;                     // 4 MB
    float* Vb    = Kb + (size_t)N_NODES * D;                     // 4 MB
    int*   winner = (int*)(Vb + (size_t)N_NODES * D);            // 256 KB
    unsigned short* nAhi = (unsigned short*)(winner + G * 1024); // 2 MB
    unsigned short* nAlo = nAhi + (size_t)N_NODES * D;           // 2 MB
    unsigned short* wThi = nAlo + (size_t)N_NODES * D;           // 2 MB (4x512x512)
    unsigned short* wTlo = wThi + (size_t)4 * D * D;             // 2 MB
    unsigned short* AOhi = wTlo + (size_t)4 * D * D;             // 2 MB
    unsigned short* AOlo = AOhi + (size_t)N_NODES * D;           // 2 MB

    // winner init + winner pass (tiny)
    init_winner_kernel<<<G * 1024 / (256 * 4), 256, 0, stream>>>((int4*)winner);
    edge_winner_kernel<<<M_EDGES / 256, 256, 0, stream>>>(senders, receivers, winner);

    split_a_kernel<<<(N_NODES * D / 8 + 255) / 256, 256, 0, stream>>>(
        nodes, nAhi, nAlo, N_NODES * D / 8);
    split_wT_kernel<<<dim3(16, 16, 4), 256, 0, stream>>>(Wq, Wk, Wv, Wo, wThi, wTlo);

    // QKV: one dispatch, z = 0/1/2 selects weights & bias & output
    GemmArgs qkv;
    qkv.Ahi = nAhi; qkv.Alo = nAlo;
    qkv.BhiT = wThi; qkv.BloT = wTlo;
    qkv.bias[0] = bq; qkv.bias[1] = bk; qkv.bias[2] = bv;
    qkv.C = Qb;   // Qb,Kb,Vb contiguous
    gemm_split_kernel<<<dim3(D / 64, N_NODES / 128, 3), 256, 0, stream>>>(qkv);

    attn_kernel<<<dim3(G, H), 1024, 0, stream>>>(Qb, Kb, Vb, edges, We, be,
                                                 winner, AOhi, AOlo);

    // output GEMM: z=0, weights at slot 3 (Wo)
    GemmArgs og;
    og.Ahi = AOhi; og.Alo = AOlo;
    og.BhiT = wThi + (size_t)3 * D * D; og.BloT = wTlo + (size_t)3 * D * D;
    og.bias[0] = bo; og.bias[1] = bo; og.bias[2] = bo;
    og.C = (float*)d_out;
    gemm_split_kernel<<<dim3(D / 64, N_NODES / 128, 1), 256, 0, stream>>>(og);
}

// Round 4
// 64.345 us; speedup vs baseline: 1.6118x; 1.3840x over previous
//
#include <hip/hip_runtime.h>

// Problem constants (fixed by setup_inputs: 64 graphs x 32 nodes)
constexpr int N_NODES = 2048;
constexpr int G       = 64;
constexpr int D       = 512;
constexpr int H       = 8;
constexpr int HD      = 64;
constexpr int E       = 16;
constexpr int M_EDGES = 16384;

typedef __attribute__((ext_vector_type(8))) short bf16x8;
typedef __attribute__((ext_vector_type(4))) float f32x4;

// ---------------------------------------------------------------------------
// bf16 helpers (round-to-nearest-even)
// ---------------------------------------------------------------------------
__device__ __forceinline__ unsigned short f2bf(float f) {
    union { float f; unsigned u; } v; v.f = f;
    unsigned r = v.u + 0x7fff + ((v.u >> 16) & 1);
    return (unsigned short)(r >> 16);
}
__device__ __forceinline__ float bf2f(unsigned short b) {
    union { unsigned u; float f; } v; v.u = ((unsigned)b) << 16; return v.f;
}

__device__ __forceinline__ void load_lds16(const void* g, void* l) {
    __builtin_amdgcn_global_load_lds(
        (const __attribute__((address_space(1))) unsigned int*)g,
        (__attribute__((address_space(3))) unsigned int*)l, 16, 0, 0);
}

// ---------------------------------------------------------------------------
// PREP kernel (one dispatch, 3 roles by blockIdx.x):
//   blocks [0,64):        per-graph edge winner (LDS atomicMax, deterministic)
//                         + precomputed bias matrix [G][H][32][32]
//   blocks [64,576):      split nodes fp32 -> bf16 hi/lo   (512 blocks)
//   blocks [576,1600):    split+transpose weights -> bf16 hi/lo (1024 blocks)
// ---------------------------------------------------------------------------
__global__ __launch_bounds__(256) void prep_kernel(
    const float* __restrict__ nodes,
    const float* __restrict__ Wq, const float* __restrict__ Wk,
    const float* __restrict__ Wv, const float* __restrict__ Wo,
    const float* __restrict__ edges, const float* __restrict__ We,
    const float* __restrict__ be,
    const int* __restrict__ snd, const int* __restrict__ rcv,
    unsigned short* __restrict__ nAhi, unsigned short* __restrict__ nAlo,
    unsigned short* __restrict__ wThi, unsigned short* __restrict__ wTlo,
    float* __restrict__ biasM)
{
    const int bid = blockIdx.x;
    const int t   = threadIdx.x;

    if (bid < G) {
        // ---- per-graph edge winner + bias matrix ----
        const int g = bid;
        __shared__ int win[1024];
        __shared__ float Wes[E][H];
        __shared__ float bes[H];
        if (t < E * H) Wes[t / H][t % H] = We[t];
        if (t < H) bes[t] = be[t];
        for (int idx = t; idx < 1024; idx += 256) win[idx] = -1;
        __syncthreads();
        // scan all edges; keep those inside graph g; last index wins (atomicMax)
        for (int it = 0; it < M_EDGES / 256; ++it) {
            int m = it * 256 + t;
            int s = snd[m], r = rcv[m];
            if ((s >> 5) == g && (r >> 5) == g)
                atomicMax(&win[((r & 31) << 5) | (s & 31)], m);
        }
        __syncthreads();
        for (int idx = t; idx < 1024; idx += 256) {
            int m = win[idx];
            float out[H];
            if (m >= 0) {
                float ef[E];
#pragma unroll
                for (int e = 0; e < E; ++e) ef[e] = edges[m * E + e];
#pragma unroll
                for (int hh = 0; hh < H; ++hh) {
                    float v = bes[hh];
#pragma unroll
                    for (int e = 0; e < E; ++e) v += ef[e] * Wes[e][hh];
                    out[hh] = v;
                }
            } else {
#pragma unroll
                for (int hh = 0; hh < H; ++hh) out[hh] = 0.f;
            }
#pragma unroll
            for (int hh = 0; hh < H; ++hh)
                biasM[(size_t)((g * H + hh) << 10) + idx] = out[hh];
        }
        return;
    }

    if (bid < G + 512) {
        // ---- split nodes: 512 blocks x 256 thr x 8 elems = 1M elems ----
        int i = (bid - G) * 256 + t;      // item index, 8 floats each
        float4 v0 = ((const float4*)nodes)[2 * i];
        float4 v1 = ((const float4*)nodes)[2 * i + 1];
        float f[8] = { v0.x, v0.y, v0.z, v0.w, v1.x, v1.y, v1.z, v1.w };
        union { unsigned short u[8]; int4 v; } ph, pl;
#pragma unroll
        for (int e = 0; e < 8; ++e) {
            unsigned short h = f2bf(f[e]);
            ph.u[e] = h;
            pl.u[e] = f2bf(f[e] - bf2f(h));
        }
        ((int4*)nAhi)[i] = ph.v;
        ((int4*)nAlo)[i] = pl.v;
        return;
    }

    {
        // ---- split + transpose weights: WtT[z][n][k] = W_z[k][n] ----
        int idx = bid - (G + 512);        // 0..1023
        int z   = idx >> 8;
        int rem = idx & 255;
        int k0  = (rem >> 4) * 32, n0 = (rem & 15) * 32;
        const float* W = (z == 0) ? Wq : (z == 1) ? Wk : (z == 2) ? Wv : Wo;
        __shared__ float tile[32][33];
        {
            int kr = t >> 3, nc4 = (t & 7) * 4;
            float4 v = *(const float4*)(W + (size_t)(k0 + kr) * D + n0 + nc4);
            tile[nc4 + 0][kr] = v.x;
            tile[nc4 + 1][kr] = v.y;
            tile[nc4 + 2][kr] = v.z;
            tile[nc4 + 3][kr] = v.w;
        }
        __syncthreads();
        {
            int nl = t >> 3, kq = (t & 7) * 4;
            union { unsigned short u[4]; ushort4 v; } h, l;
#pragma unroll
            for (int j = 0; j < 4; ++j) {
                float f = tile[nl][kq + j];
                unsigned short hb = f2bf(f);
                h.u[j] = hb;
                l.u[j] = f2bf(f - bf2f(hb));
            }
            size_t base = (size_t)z * D * D + (size_t)(n0 + nl) * D + k0 + kq;
            *(ushort4*)(wThi + base) = h.v;
            *(ushort4*)(wTlo + base) = l.v;
        }
    }
}

// ---------------------------------------------------------------------------
// Fused split-3 MFMA GEMM: C = Ahi@B'hi + Ahi@B'lo + Alo@B'hi + bias
// (B given transposed [N][K]).  Tile 64x64, BK=32, 256 thr = 4 waves (2x2),
// wave tile 32x32. Per K-step: stage 4 tiles (Ahi,Alo,Bhi,Blo; 16 KB),
// 8 ds_read_b128 + 12 MFMA per wave.  LDS double-buffered (32 KB).
// Swizzle: 16B-slot ^= (row>>1)&3  -> 8 distinct banks per 16-lane read.
// ---------------------------------------------------------------------------
struct GemmArgs {
    const unsigned short *Ahi, *Alo, *BhiT, *BloT;
    const float* bias[3];
    float* C;
};

__global__ __launch_bounds__(256) void gemm_fused_kernel(GemmArgs a)
{
    const int z = blockIdx.z;
    const unsigned short* Ahi  = a.Ahi;
    const unsigned short* Alo  = a.Alo;
    const unsigned short* Bhi  = a.BhiT + (size_t)z * D * D;
    const unsigned short* Blo  = a.BloT + (size_t)z * D * D;
    const float* bias = a.bias[z];
    float* C = a.C + (size_t)z * (size_t)N_NODES * D;

    __shared__ __align__(16) char lds[2][4][4096];   // [buf][Ahi,Alo,Bhi,Blo]

    const int t    = threadIdx.x;
    const int lane = t & 63;
    const int w    = t >> 6;
    const int wm   = w >> 1, wn = w & 1;     // wave grid 2x2 over 64x64
    const int row0 = blockIdx.y * 64;
    const int col0 = blockIdx.x * 64;

    // staging: thread t writes physical LDS bytes [t*16, t*16+16) of each tile.
    // physical cell: prow = t>>2 (64B rows), pslot = t&3. Global source is
    // inverse-swizzled: logical slot = pslot ^ ((prow>>1)&3).
    const int prow  = t >> 2;
    const int lslot = (t & 3) ^ ((t >> 3) & 3);
    const size_t aOff = (size_t)(row0 + prow) * 1024 + lslot * 16;
    const size_t bOff = (size_t)(col0 + prow) * 1024 + lslot * 16;

    auto stage = [&](int buf, int k0) {
        load_lds16((const char*)Ahi + aOff + k0 * 2, &lds[buf][0][t * 16]);
        load_lds16((const char*)Alo + aOff + k0 * 2, &lds[buf][1][t * 16]);
        load_lds16((const char*)Bhi + bOff + k0 * 2, &lds[buf][2][t * 16]);
        load_lds16((const char*)Blo + bOff + k0 * 2, &lds[buf][3][t * 16]);
    };

    f32x4 acc[2][2] = {};

    stage(0, 0);
    __syncthreads();

    int cur = 0;
    for (int step = 0; step < 16; ++step) {
        if (step < 15) stage(cur ^ 1, (step + 1) * 32);

        bf16x8 fahi[2], falo[2], fbhi[2], fblo[2];
#pragma unroll
        for (int mf = 0; mf < 2; ++mf) {
            int row = wm * 32 + mf * 16 + (lane & 15);
            int sl  = (((lane >> 4) ^ ((row >> 1) & 3)) << 4);
            fahi[mf] = *(const bf16x8*)&lds[cur][0][row * 64 + sl];
            falo[mf] = *(const bf16x8*)&lds[cur][1][row * 64 + sl];
        }
#pragma unroll
        for (int nf = 0; nf < 2; ++nf) {
            int row = wn * 32 + nf * 16 + (lane & 15);
            int sl  = (((lane >> 4) ^ ((row >> 1) & 3)) << 4);
            fbhi[nf] = *(const bf16x8*)&lds[cur][2][row * 64 + sl];
            fblo[nf] = *(const bf16x8*)&lds[cur][3][row * 64 + sl];
        }
#pragma unroll
        for (int mf = 0; mf < 2; ++mf)
#pragma unroll
            for (int nf = 0; nf < 2; ++nf) {
                acc[mf][nf] = __builtin_amdgcn_mfma_f32_16x16x32_bf16(
                    fahi[mf], fbhi[nf], acc[mf][nf], 0, 0, 0);
                acc[mf][nf] = __builtin_amdgcn_mfma_f32_16x16x32_bf16(
                    fahi[mf], fblo[nf], acc[mf][nf], 0, 0, 0);
                acc[mf][nf] = __builtin_amdgcn_mfma_f32_16x16x32_bf16(
                    falo[mf], fbhi[nf], acc[mf][nf], 0, 0, 0);
            }

        __syncthreads();
        cur ^= 1;
    }

    // epilogue: C/D layout col=lane&15, row=(lane>>4)*4+reg
#pragma unroll
    for (int mf = 0; mf < 2; ++mf)
#pragma unroll
        for (int nf = 0; nf < 2; ++nf) {
            int col = col0 + wn * 32 + nf * 16 + (lane & 15);
            float bv = bias[col];
#pragma unroll
            for (int r = 0; r < 4; ++r) {
                int row = row0 + wm * 32 + mf * 16 + (lane >> 4) * 4 + r;
                C[(size_t)row * D + col] = acc[mf][nf][r] + bv;
            }
        }
}

// ---------------------------------------------------------------------------
// Per-(graph, head) block-diagonal attention; bias precomputed by prep;
// writes output pre-split bf16.
// ---------------------------------------------------------------------------
__global__ __launch_bounds__(1024) void attn_kernel(
    const float* __restrict__ Q, const float* __restrict__ K,
    const float* __restrict__ V, const float* __restrict__ biasM,
    unsigned short* __restrict__ AOhi, unsigned short* __restrict__ AOlo)
{
    const int g = blockIdx.x;
    const int h = blockIdx.y;
    __shared__ float Qs[32][64];
    __shared__ float Ks[32][65];
    __shared__ float Vs[32][65];
    __shared__ float P[32][33];

    const int tid = threadIdx.x;
    for (int idx = tid; idx < 32 * 64; idx += 1024) {
        int n = idx >> 6, d = idx & 63;
        size_t ga = (size_t)(g * 32 + n) * D + h * HD + d;
        Qs[n][d] = Q[ga];
        Ks[n][d] = K[ga];
        Vs[n][d] = V[ga];
    }
    __syncthreads();

    const int i = tid >> 5;        // query row (receiver)
    const int j = tid & 31;        // key col (sender)
    float s = 0.f;
#pragma unroll
    for (int d = 0; d < 64; ++d) s += Qs[i][d] * Ks[j][d];
    s = s * 0.125f + biasM[(size_t)((g * H + h) << 10) + (i << 5) + j];

    float mx = s;
#pragma unroll
    for (int o = 16; o > 0; o >>= 1) mx = fmaxf(mx, __shfl_xor(mx, o));
    float p = __expf(s - mx);
    float sum = p;
#pragma unroll
    for (int o = 16; o > 0; o >>= 1) sum += __shfl_xor(sum, o);
    p /= sum;
    P[i][j] = p;
    __syncthreads();

    float o0 = 0.f, o1 = 0.f;
#pragma unroll
    for (int kk = 0; kk < 32; ++kk) {
        float pv = P[i][kk];
        o0 += pv * Vs[kk][j];
        o1 += pv * Vs[kk][j + 32];
    }
    size_t oa = (size_t)(g * 32 + i) * D + h * HD;
    unsigned short h0 = f2bf(o0);
    unsigned short h1 = f2bf(o1);
    AOhi[oa + j]      = h0;
    AOlo[oa + j]      = f2bf(o0 - bf2f(h0));
    AOhi[oa + j + 32] = h1;
    AOlo[oa + j + 32] = f2bf(o1 - bf2f(h1));
}

// ---------------------------------------------------------------------------
extern "C" void kernel_launch(void* const* d_in, const int* in_sizes, int n_in,
                              void* d_out, int out_size, void* d_ws, size_t ws_size,
                              hipStream_t stream)
{
    const float* nodes = (const float*)d_in[0];
    const float* edges = (const float*)d_in[1];
    const float* Wq    = (const float*)d_in[2];
    const float* bq    = (const float*)d_in[3];
    const float* Wk    = (const float*)d_in[4];
    const float* bk    = (const float*)d_in[5];
    const float* Wv    = (const float*)d_in[6];
    const float* bv    = (const float*)d_in[7];
    const float* Wo    = (const float*)d_in[8];
    const float* bo    = (const float*)d_in[9];
    const float* We    = (const float*)d_in[10];
    const float* be    = (const float*)d_in[11];
    const int* senders   = (const int*)d_in[13];
    const int* receivers = (const int*)d_in[14];

    // workspace layout
    char* ws = (char*)d_ws;
    float* Qb    = (float*)ws;                                   // 4 MB
    float* Kb    = Qb + (size_t)N_NODES * D;                     // 4 MB
    float* Vb    = Kb + (size_t)N_NODES * D;                     // 4 MB
    float* biasM = Vb + (size_t)N_NODES * D;                     // 2 MB
    unsigned short* nAhi = (unsigned short*)(biasM + (size_t)G * H * 1024);
    unsigned short* nAlo = nAhi + (size_t)N_NODES * D;           // 2 MB each
    unsigned short* wThi = nAlo + (size_t)N_NODES * D;           // 2 MB (4x512x512)
    unsigned short* wTlo = wThi + (size_t)4 * D * D;             // 2 MB
    unsigned short* AOhi = wTlo + (size_t)4 * D * D;             // 2 MB
    unsigned short* AOlo = AOhi + (size_t)N_NODES * D;           // 2 MB

    // 1) prep: edge bias matrix + node split + weight split/transpose
    prep_kernel<<<G + 512 + 1024, 256, 0, stream>>>(
        nodes, Wq, Wk, Wv, Wo, edges, We, be, senders, receivers,
        nAhi, nAlo, wThi, wTlo, biasM);

    // 2) QKV GEMM (z = 0/1/2)
    GemmArgs qkv;
    qkv.Ahi = nAhi; qkv.Alo = nAlo;
    qkv.BhiT = wThi; qkv.BloT = wTlo;
    qkv.bias[0] = bq; qkv.bias[1] = bk; qkv.bias[2] = bv;
    qkv.C = Qb;   // Qb,Kb,Vb contiguous
    gemm_fused_kernel<<<dim3(D / 64, N_NODES / 64, 3), 256, 0, stream>>>(qkv);

    // 3) attention
    attn_kernel<<<dim3(G, H), 1024, 0, stream>>>(Qb, Kb, Vb, biasM, AOhi, AOlo);

    // 4) output GEMM (Wo at slot 3)
    GemmArgs og;
    og.Ahi = AOhi; og.Alo = AOlo;
    og.BhiT = wThi + (size_t)3 * D * D; og.BloT = wTlo + (size_t)3 * D * D;
    og.bias[0] = bo; og.bias[1] = bo; og.bias[2] = bo;
    og.C = (float*)d_out;
    gemm_fused_kernel<<<dim3(D / 64, N_NODES / 64, 1), 256, 0, stream>>>(og);
}

// Round 5
// 55.699 us; speedup vs baseline: 1.8620x; 1.1552x over previous
//
#include <hip/hip_runtime.h>

// Problem constants (fixed by setup_inputs: 64 graphs x 32 nodes)
constexpr int N_NODES = 2048;
constexpr int G       = 64;
constexpr int D       = 512;
constexpr int H       = 8;
constexpr int HD      = 64;
constexpr int E       = 16;
constexpr int M_EDGES = 16384;

typedef __attribute__((ext_vector_type(8))) _Float16 f16x8;
typedef __attribute__((ext_vector_type(4))) float f32x4;

__device__ __forceinline__ void load_lds16(const void* g, void* l) {
    __builtin_amdgcn_global_load_lds(
        (const __attribute__((address_space(1))) unsigned int*)g,
        (__attribute__((address_space(3))) unsigned int*)l, 16, 0, 0);
}

// ---------------------------------------------------------------------------
// PREP kernel (one dispatch, 3 roles by blockIdx.x):
//   blocks [0,64):     per-graph edge winner (LDS atomicMax, deterministic)
//                      + precomputed bias matrix [G][H][32][32]
//   blocks [64,576):   cast nodes fp32 -> fp16            (512 blocks)
//   blocks [576,1600): split+transpose weights -> fp16 hi + lo*2048 (1024 blocks)
// ---------------------------------------------------------------------------
__global__ __launch_bounds__(256) void prep_kernel(
    const float* __restrict__ nodes,
    const float* __restrict__ Wq, const float* __restrict__ Wk,
    const float* __restrict__ Wv, const float* __restrict__ Wo,
    const float* __restrict__ edges, const float* __restrict__ We,
    const float* __restrict__ be,
    const int* __restrict__ snd, const int* __restrict__ rcv,
    _Float16* __restrict__ nA16,
    _Float16* __restrict__ wThi, _Float16* __restrict__ wTlo,
    float* __restrict__ biasM)
{
    const int bid = blockIdx.x;
    const int t   = threadIdx.x;

    if (bid < G) {
        // ---- per-graph edge winner + bias matrix ----
        const int g = bid;
        __shared__ int win[1024];
        __shared__ float Wes[E][H];
        __shared__ float bes[H];
        if (t < E * H) Wes[t / H][t % H] = We[t];
        if (t < H) bes[t] = be[t];
        for (int idx = t; idx < 1024; idx += 256) win[idx] = -1;
        __syncthreads();
        for (int it = 0; it < M_EDGES / 256; ++it) {
            int m = it * 256 + t;
            int s = snd[m], r = rcv[m];
            if ((s >> 5) == g && (r >> 5) == g)
                atomicMax(&win[((r & 31) << 5) | (s & 31)], m);
        }
        __syncthreads();
        for (int idx = t; idx < 1024; idx += 256) {
            int m = win[idx];
            float out[H];
            if (m >= 0) {
                float ef[E];
#pragma unroll
                for (int e = 0; e < E; ++e) ef[e] = edges[m * E + e];
#pragma unroll
                for (int hh = 0; hh < H; ++hh) {
                    float v = bes[hh];
#pragma unroll
                    for (int e = 0; e < E; ++e) v += ef[e] * Wes[e][hh];
                    out[hh] = v;
                }
            } else {
#pragma unroll
                for (int hh = 0; hh < H; ++hh) out[hh] = 0.f;
            }
#pragma unroll
            for (int hh = 0; hh < H; ++hh)
                biasM[(size_t)((g * H + hh) << 10) + idx] = out[hh];
        }
        return;
    }

    if (bid < G + 512) {
        // ---- cast nodes to fp16: 512 blocks x 256 thr x 8 elems ----
        int i = (bid - G) * 256 + t;
        float4 v0 = ((const float4*)nodes)[2 * i];
        float4 v1 = ((const float4*)nodes)[2 * i + 1];
        float f[8] = { v0.x, v0.y, v0.z, v0.w, v1.x, v1.y, v1.z, v1.w };
        union { _Float16 h[8]; int4 v; } p;
#pragma unroll
        for (int e = 0; e < 8; ++e) p.h[e] = (_Float16)f[e];
        ((int4*)nA16)[i] = p.v;
        return;
    }

    {
        // ---- split + transpose weights: WtT[z][n][k] = W_z[k][n] ----
        int idx = bid - (G + 512);        // 0..1023
        int z   = idx >> 8;
        int rem = idx & 255;
        int k0  = (rem >> 4) * 32, n0 = (rem & 15) * 32;
        const float* W = (z == 0) ? Wq : (z == 1) ? Wk : (z == 2) ? Wv : Wo;
        __shared__ float tile[32][33];
        {
            int kr = t >> 3, nc4 = (t & 7) * 4;
            float4 v = *(const float4*)(W + (size_t)(k0 + kr) * D + n0 + nc4);
            tile[nc4 + 0][kr] = v.x;
            tile[nc4 + 1][kr] = v.y;
            tile[nc4 + 2][kr] = v.z;
            tile[nc4 + 3][kr] = v.w;
        }
        __syncthreads();
        {
            int nl = t >> 3, kq = (t & 7) * 4;
            union { _Float16 h[4]; uint2 v; } hi, lo;
#pragma unroll
            for (int j = 0; j < 4; ++j) {
                float f = tile[nl][kq + j];
                _Float16 hb = (_Float16)f;
                hi.h[j] = hb;
                lo.h[j] = (_Float16)((f - (float)hb) * 2048.0f);  // scaled lo
            }
            size_t base = (size_t)z * D * D + (size_t)(n0 + nl) * D + k0 + kq;
            *(uint2*)(wThi + base) = hi.v;
            *(uint2*)(wTlo + base) = lo.v;
        }
    }
}

// ---------------------------------------------------------------------------
// fp16 2-product MFMA GEMM:  C = A@B'hi + (A@B'lo)*2^-11 + bias
// A fp16 [M][K]; B transposed fp16 [N][K] (hi and 2^11-scaled lo).
// Tile 64x64, BK=64, 256 thr = 4 waves (2x2), wave tile 32x32.
// Per step: stage 3 tiles (8 KB each), 12 ds_read_b128 + 16 MFMA per wave.
// LDS double-buffered (48 KB -> 3 blocks/CU). Rows are 128 B; 16B-slot
// swizzle slot ^= row&7 puts reads at the structural b128 minimum.
// ---------------------------------------------------------------------------
struct GemmArgs {
    const _Float16 *A, *BhiT, *BloT;
    const float* bias[3];
    float* C;
};

__global__ __launch_bounds__(256) void gemm_f16_kernel(GemmArgs a)
{
    const int z = blockIdx.z;
    const _Float16* A   = a.A;
    const _Float16* Bhi = a.BhiT + (size_t)z * D * D;
    const _Float16* Blo = a.BloT + (size_t)z * D * D;
    const float* bias = a.bias[z];
    float* C = a.C + (size_t)z * (size_t)N_NODES * D;

    __shared__ __align__(16) char lds[2][3][8192];   // [buf][A,Bhi,Blo]

    const int t    = threadIdx.x;
    const int lane = t & 63;
    const int w    = t >> 6;
    const int wm   = w >> 1, wn = w & 1;     // wave grid 2x2 over 64x64
    const int row0 = blockIdx.y * 64;
    const int col0 = blockIdx.x * 64;

    // staging: tile = 64 rows x 128 B; chunk c (0..511): prow=c>>3, pslot=c&7.
    // thread t covers chunks t and 256+t (prow1 = prow0+32, same lslot).
    // logical slot = pslot ^ (prow&7); global source inverse-swizzled.
    const int prow0 = t >> 3;
    const int lslot = (t & 7) ^ (prow0 & 7);

    auto stage = [&](int buf, int k0) {
        size_t a0 = (size_t)(row0 + prow0) * 1024 + k0 * 2 + lslot * 16;
        size_t a1 = a0 + 32 * 1024;
        size_t b0 = (size_t)(col0 + prow0) * 1024 + k0 * 2 + lslot * 16;
        size_t b1 = b0 + 32 * 1024;
        load_lds16((const char*)A + a0,   &lds[buf][0][t * 16]);
        load_lds16((const char*)A + a1,   &lds[buf][0][4096 + t * 16]);
        load_lds16((const char*)Bhi + b0, &lds[buf][1][t * 16]);
        load_lds16((const char*)Bhi + b1, &lds[buf][1][4096 + t * 16]);
        load_lds16((const char*)Blo + b0, &lds[buf][2][t * 16]);
        load_lds16((const char*)Blo + b1, &lds[buf][2][4096 + t * 16]);
    };

    f32x4 acch[2][2] = {}, accl[2][2] = {};

    stage(0, 0);
    __syncthreads();

    int cur = 0;
    for (int step = 0; step < 8; ++step) {
        if (step < 7) stage(cur ^ 1, (step + 1) * 64);

        f16x8 fa[2][2], fbh[2][2], fbl[2][2];
#pragma unroll
        for (int mf = 0; mf < 2; ++mf) {
            int row = wm * 32 + mf * 16 + (lane & 15);
#pragma unroll
            for (int ks = 0; ks < 2; ++ks) {
                int ps = ((ks * 4 + (lane >> 4)) ^ (row & 7)) << 4;
                fa[mf][ks] = *(const f16x8*)&lds[cur][0][row * 128 + ps];
            }
        }
#pragma unroll
        for (int nf = 0; nf < 2; ++nf) {
            int row = wn * 32 + nf * 16 + (lane & 15);
#pragma unroll
            for (int ks = 0; ks < 2; ++ks) {
                int ps = ((ks * 4 + (lane >> 4)) ^ (row & 7)) << 4;
                fbh[nf][ks] = *(const f16x8*)&lds[cur][1][row * 128 + ps];
                fbl[nf][ks] = *(const f16x8*)&lds[cur][2][row * 128 + ps];
            }
        }
#pragma unroll
        for (int mf = 0; mf < 2; ++mf)
#pragma unroll
            for (int nf = 0; nf < 2; ++nf)
#pragma unroll
                for (int ks = 0; ks < 2; ++ks) {
                    acch[mf][nf] = __builtin_amdgcn_mfma_f32_16x16x32_f16(
                        fa[mf][ks], fbh[nf][ks], acch[mf][nf], 0, 0, 0);
                    accl[mf][nf] = __builtin_amdgcn_mfma_f32_16x16x32_f16(
                        fa[mf][ks], fbl[nf][ks], accl[mf][nf], 0, 0, 0);
                }

        __syncthreads();
        cur ^= 1;
    }

    // epilogue: C/D layout col=lane&15, row=(lane>>4)*4+reg
    constexpr float kLoScale = 1.0f / 2048.0f;
#pragma unroll
    for (int mf = 0; mf < 2; ++mf)
#pragma unroll
        for (int nf = 0; nf < 2; ++nf) {
            int col = col0 + wn * 32 + nf * 16 + (lane & 15);
            float bv = bias[col];
#pragma unroll
            for (int r = 0; r < 4; ++r) {
                int row = row0 + wm * 32 + mf * 16 + (lane >> 4) * 4 + r;
                C[(size_t)row * D + col] =
                    acch[mf][nf][r] + accl[mf][nf][r] * kLoScale + bv;
            }
        }
}

// ---------------------------------------------------------------------------
// Per-(graph, head) block-diagonal attention; bias precomputed by prep;
// writes output as fp16 (A-operand of the output GEMM).
// ---------------------------------------------------------------------------
__global__ __launch_bounds__(1024) void attn_kernel(
    const float* __restrict__ Q, const float* __restrict__ K,
    const float* __restrict__ V, const float* __restrict__ biasM,
    _Float16* __restrict__ AO16)
{
    const int g = blockIdx.x;
    const int h = blockIdx.y;
    __shared__ float Qs[32][64];
    __shared__ float Ks[32][65];
    __shared__ float Vs[32][65];
    __shared__ float P[32][33];

    const int tid = threadIdx.x;
    for (int idx = tid; idx < 32 * 64; idx += 1024) {
        int n = idx >> 6, d = idx & 63;
        size_t ga = (size_t)(g * 32 + n) * D + h * HD + d;
        Qs[n][d] = Q[ga];
        Ks[n][d] = K[ga];
        Vs[n][d] = V[ga];
    }
    __syncthreads();

    const int i = tid >> 5;        // query row (receiver)
    const int j = tid & 31;        // key col (sender)
    float s = 0.f;
#pragma unroll
    for (int d = 0; d < 64; ++d) s += Qs[i][d] * Ks[j][d];
    s = s * 0.125f + biasM[(size_t)((g * H + h) << 10) + (i << 5) + j];

    float mx = s;
#pragma unroll
    for (int o = 16; o > 0; o >>= 1) mx = fmaxf(mx, __shfl_xor(mx, o));
    float p = __expf(s - mx);
    float sum = p;
#pragma unroll
    for (int o = 16; o > 0; o >>= 1) sum += __shfl_xor(sum, o);
    p /= sum;
    P[i][j] = p;
    __syncthreads();

    float o0 = 0.f, o1 = 0.f;
#pragma unroll
    for (int kk = 0; kk < 32; ++kk) {
        float pv = P[i][kk];
        o0 += pv * Vs[kk][j];
        o1 += pv * Vs[kk][j + 32];
    }
    size_t oa = (size_t)(g * 32 + i) * D + h * HD;
    AO16[oa + j]      = (_Float16)o0;
    AO16[oa + j + 32] = (_Float16)o1;
}

// ---------------------------------------------------------------------------
extern "C" void kernel_launch(void* const* d_in, const int* in_sizes, int n_in,
                              void* d_out, int out_size, void* d_ws, size_t ws_size,
                              hipStream_t stream)
{
    const float* nodes = (const float*)d_in[0];
    const float* edges = (const float*)d_in[1];
    const float* Wq    = (const float*)d_in[2];
    const float* bq    = (const float*)d_in[3];
    const float* Wk    = (const float*)d_in[4];
    const float* bk    = (const float*)d_in[5];
    const float* Wv    = (const float*)d_in[6];
    const float* bv    = (const float*)d_in[7];
    const float* Wo    = (const float*)d_in[8];
    const float* bo    = (const float*)d_in[9];
    const float* We    = (const float*)d_in[10];
    const float* be    = (const float*)d_in[11];
    const int* senders   = (const int*)d_in[13];
    const int* receivers = (const int*)d_in[14];

    // workspace layout
    char* ws = (char*)d_ws;
    float* Qb    = (float*)ws;                                   // 4 MB
    float* Kb    = Qb + (size_t)N_NODES * D;                     // 4 MB
    float* Vb    = Kb + (size_t)N_NODES * D;                     // 4 MB
    float* biasM = Vb + (size_t)N_NODES * D;                     // 2 MB
    _Float16* nA16 = (_Float16*)(biasM + (size_t)G * H * 1024);  // 2 MB
    _Float16* wThi = nA16 + (size_t)N_NODES * D;                 // 2 MB (4x512x512)
    _Float16* wTlo = wThi + (size_t)4 * D * D;                   // 2 MB
    _Float16* AO16 = wTlo + (size_t)4 * D * D;                   // 2 MB

    // 1) prep: edge bias matrix + node cast + weight split/transpose
    prep_kernel<<<G + 512 + 1024, 256, 0, stream>>>(
        nodes, Wq, Wk, Wv, Wo, edges, We, be, senders, receivers,
        nA16, wThi, wTlo, biasM);

    // 2) QKV GEMM (z = 0/1/2)
    GemmArgs qkv;
    qkv.A = nA16;
    qkv.BhiT = wThi; qkv.BloT = wTlo;
    qkv.bias[0] = bq; qkv.bias[1] = bk; qkv.bias[2] = bv;
    qkv.C = Qb;   // Qb,Kb,Vb contiguous
    gemm_f16_kernel<<<dim3(D / 64, N_NODES / 64, 3), 256, 0, stream>>>(qkv);

    // 3) attention
    attn_kernel<<<dim3(G, H), 1024, 0, stream>>>(Qb, Kb, Vb, biasM, AO16);

    // 4) output GEMM (Wo at slot 3)
    GemmArgs og;
    og.A = AO16;
    og.BhiT = wThi + (size_t)3 * D * D; og.BloT = wTlo + (size_t)3 * D * D;
    og.bias[0] = bo; og.bias[1] = bo; og.bias[2] = bo;
    og.C = (float*)d_out;
    gemm_f16_kernel<<<dim3(D / 64, N_NODES / 64, 1), 256, 0, stream>>>(og);
}

// Round 6
// 52.074 us; speedup vs baseline: 1.9916x; 1.0696x over previous
//
#include <hip/hip_runtime.h>

// Problem constants (fixed by setup_inputs: 64 graphs x 32 nodes)
constexpr int N_NODES = 2048;
constexpr int G       = 64;
constexpr int D       = 512;
constexpr int H       = 8;
constexpr int HD      = 64;
constexpr int E       = 16;
constexpr int M_EDGES = 16384;

typedef __attribute__((ext_vector_type(8))) _Float16 f16x8;
typedef __attribute__((ext_vector_type(4))) float f32x4;

__device__ __forceinline__ void load_lds16(const void* g, void* l) {
    __builtin_amdgcn_global_load_lds(
        (const __attribute__((address_space(1))) unsigned int*)g,
        (__attribute__((address_space(3))) unsigned int*)l, 16, 0, 0);
}

// ---------------------------------------------------------------------------
// PREP kernel (one dispatch, 3 roles by blockIdx.x):
//   blocks [0,64):     per-graph edge winner (LDS atomicMax, deterministic)
//                      + precomputed bias matrix [G][H][32][32]
//   blocks [64,576):   cast nodes fp32 -> fp16            (512 blocks)
//   blocks [576,1600): transpose+cast weights -> fp16     (1024 blocks)
// ---------------------------------------------------------------------------
__global__ __launch_bounds__(256) void prep_kernel(
    const float* __restrict__ nodes,
    const float* __restrict__ Wq, const float* __restrict__ Wk,
    const float* __restrict__ Wv, const float* __restrict__ Wo,
    const float* __restrict__ edges, const float* __restrict__ We,
    const float* __restrict__ be,
    const int* __restrict__ snd, const int* __restrict__ rcv,
    _Float16* __restrict__ nA16, _Float16* __restrict__ wT16,
    float* __restrict__ biasM)
{
    const int bid = blockIdx.x;
    const int t   = threadIdx.x;

    if (bid < G) {
        // ---- per-graph edge winner + bias matrix ----
        const int g = bid;
        __shared__ int win[1024];
        __shared__ float Wes[E][H];
        __shared__ float bes[H];
        if (t < E * H) Wes[t / H][t % H] = We[t];
        if (t < H) bes[t] = be[t];
        for (int idx = t; idx < 1024; idx += 256) win[idx] = -1;
        __syncthreads();
        for (int it = 0; it < M_EDGES / 256; ++it) {
            int m = it * 256 + t;
            int s = snd[m], r = rcv[m];
            if ((s >> 5) == g && (r >> 5) == g)
                atomicMax(&win[((r & 31) << 5) | (s & 31)], m);
        }
        __syncthreads();
        for (int idx = t; idx < 1024; idx += 256) {
            int m = win[idx];
            float out[H];
            if (m >= 0) {
                float ef[E];
#pragma unroll
                for (int e = 0; e < E; ++e) ef[e] = edges[m * E + e];
#pragma unroll
                for (int hh = 0; hh < H; ++hh) {
                    float v = bes[hh];
#pragma unroll
                    for (int e = 0; e < E; ++e) v += ef[e] * Wes[e][hh];
                    out[hh] = v;
                }
            } else {
#pragma unroll
                for (int hh = 0; hh < H; ++hh) out[hh] = 0.f;
            }
#pragma unroll
            for (int hh = 0; hh < H; ++hh)
                biasM[(size_t)((g * H + hh) << 10) + idx] = out[hh];
        }
        return;
    }

    if (bid < G + 512) {
        // ---- cast nodes to fp16: 512 blocks x 256 thr x 8 elems ----
        int i = (bid - G) * 256 + t;
        float4 v0 = ((const float4*)nodes)[2 * i];
        float4 v1 = ((const float4*)nodes)[2 * i + 1];
        float f[8] = { v0.x, v0.y, v0.z, v0.w, v1.x, v1.y, v1.z, v1.w };
        union { _Float16 h[8]; int4 v; } p;
#pragma unroll
        for (int e = 0; e < 8; ++e) p.h[e] = (_Float16)f[e];
        ((int4*)nA16)[i] = p.v;
        return;
    }

    {
        // ---- transpose + cast weights: WT[z][n][k] = W_z[k][n] ----
        int idx = bid - (G + 512);        // 0..1023
        int z   = idx >> 8;
        int rem = idx & 255;
        int k0  = (rem >> 4) * 32, n0 = (rem & 15) * 32;
        const float* W = (z == 0) ? Wq : (z == 1) ? Wk : (z == 2) ? Wv : Wo;
        __shared__ float tile[32][33];
        {
            int kr = t >> 3, nc4 = (t & 7) * 4;
            float4 v = *(const float4*)(W + (size_t)(k0 + kr) * D + n0 + nc4);
            tile[nc4 + 0][kr] = v.x;
            tile[nc4 + 1][kr] = v.y;
            tile[nc4 + 2][kr] = v.z;
            tile[nc4 + 3][kr] = v.w;
        }
        __syncthreads();
        {
            int nl = t >> 3, kq = (t & 7) * 4;
            union { _Float16 h[4]; uint2 v; } hi;
#pragma unroll
            for (int j = 0; j < 4; ++j)
                hi.h[j] = (_Float16)tile[nl][kq + j];
            size_t base = (size_t)z * D * D + (size_t)(n0 + nl) * D + k0 + kq;
            *(uint2*)(wT16 + base) = hi.v;
        }
    }
}

// ---------------------------------------------------------------------------
// Plain fp16 MFMA GEMM:  C = A@B' + bias  (B given transposed [N][K])
// Tile 64x64, BK=64, 256 thr = 4 waves (2x2), wave tile 32x32.
// Per step: stage 2 tiles (8 KB each), 8 ds_read_b128 + 8 MFMA per wave.
// LDS double-buffered (32 KB -> 4 blocks/CU possible). Rows are 128 B;
// 16B-slot swizzle slot ^= row&7 puts reads at the structural b128 minimum.
// ---------------------------------------------------------------------------
struct GemmArgs {
    const _Float16 *A, *BT;
    const float* bias[3];
    float* C;
};

__global__ __launch_bounds__(256) void gemm_f16_kernel(GemmArgs a)
{
    const int z = blockIdx.z;
    const _Float16* A = a.A;
    const _Float16* B = a.BT + (size_t)z * D * D;
    const float* bias = a.bias[z];
    float* C = a.C + (size_t)z * (size_t)N_NODES * D;

    __shared__ __align__(16) char lds[2][2][8192];   // [buf][A,B]

    const int t    = threadIdx.x;
    const int lane = t & 63;
    const int w    = t >> 6;
    const int wm   = w >> 1, wn = w & 1;     // wave grid 2x2 over 64x64
    const int row0 = blockIdx.y * 64;
    const int col0 = blockIdx.x * 64;

    // staging: tile = 64 rows x 128 B; chunk c (0..511): prow=c>>3, pslot=c&7.
    // thread t covers chunks t and 256+t (prow1 = prow0+32, same lslot).
    // logical slot = pslot ^ (prow&7); global source inverse-swizzled.
    const int prow0 = t >> 3;
    const int lslot = (t & 7) ^ (prow0 & 7);

    auto stage = [&](int buf, int k0) {
        size_t a0 = (size_t)(row0 + prow0) * 1024 + k0 * 2 + lslot * 16;
        size_t a1 = a0 + 32 * 1024;
        size_t b0 = (size_t)(col0 + prow0) * 1024 + k0 * 2 + lslot * 16;
        size_t b1 = b0 + 32 * 1024;
        load_lds16((const char*)A + a0, &lds[buf][0][t * 16]);
        load_lds16((const char*)A + a1, &lds[buf][0][4096 + t * 16]);
        load_lds16((const char*)B + b0, &lds[buf][1][t * 16]);
        load_lds16((const char*)B + b1, &lds[buf][1][4096 + t * 16]);
    };

    f32x4 acc[2][2] = {};

    stage(0, 0);
    __syncthreads();

    int cur = 0;
    for (int step = 0; step < 8; ++step) {
        if (step < 7) stage(cur ^ 1, (step + 1) * 64);

        f16x8 fa[2][2], fb[2][2];
#pragma unroll
        for (int mf = 0; mf < 2; ++mf) {
            int row = wm * 32 + mf * 16 + (lane & 15);
#pragma unroll
            for (int ks = 0; ks < 2; ++ks) {
                int ps = ((ks * 4 + (lane >> 4)) ^ (row & 7)) << 4;
                fa[mf][ks] = *(const f16x8*)&lds[cur][0][row * 128 + ps];
            }
        }
#pragma unroll
        for (int nf = 0; nf < 2; ++nf) {
            int row = wn * 32 + nf * 16 + (lane & 15);
#pragma unroll
            for (int ks = 0; ks < 2; ++ks) {
                int ps = ((ks * 4 + (lane >> 4)) ^ (row & 7)) << 4;
                fb[nf][ks] = *(const f16x8*)&lds[cur][1][row * 128 + ps];
            }
        }
#pragma unroll
        for (int mf = 0; mf < 2; ++mf)
#pragma unroll
            for (int nf = 0; nf < 2; ++nf)
#pragma unroll
                for (int ks = 0; ks < 2; ++ks)
                    acc[mf][nf] = __builtin_amdgcn_mfma_f32_16x16x32_f16(
                        fa[mf][ks], fb[nf][ks], acc[mf][nf], 0, 0, 0);

        __syncthreads();
        cur ^= 1;
    }

    // epilogue: C/D layout col=lane&15, row=(lane>>4)*4+reg
#pragma unroll
    for (int mf = 0; mf < 2; ++mf)
#pragma unroll
        for (int nf = 0; nf < 2; ++nf) {
            int col = col0 + wn * 32 + nf * 16 + (lane & 15);
            float bv = bias[col];
#pragma unroll
            for (int r = 0; r < 4; ++r) {
                int row = row0 + wm * 32 + mf * 16 + (lane >> 4) * 4 + r;
                C[(size_t)row * D + col] = acc[mf][nf][r] + bv;
            }
        }
}

// ---------------------------------------------------------------------------
// Per-(graph, head) block-diagonal attention; bias precomputed by prep;
// writes output as fp16 (A-operand of the output GEMM).
// ---------------------------------------------------------------------------
__global__ __launch_bounds__(1024) void attn_kernel(
    const float* __restrict__ Q, const float* __restrict__ K,
    const float* __restrict__ V, const float* __restrict__ biasM,
    _Float16* __restrict__ AO16)
{
    const int g = blockIdx.x;
    const int h = blockIdx.y;
    __shared__ float Qs[32][64];
    __shared__ float Ks[32][65];
    __shared__ float Vs[32][65];
    __shared__ float P[32][33];

    const int tid = threadIdx.x;
    for (int idx = tid; idx < 32 * 64; idx += 1024) {
        int n = idx >> 6, d = idx & 63;
        size_t ga = (size_t)(g * 32 + n) * D + h * HD + d;
        Qs[n][d] = Q[ga];
        Ks[n][d] = K[ga];
        Vs[n][d] = V[ga];
    }
    __syncthreads();

    const int i = tid >> 5;        // query row (receiver)
    const int j = tid & 31;        // key col (sender)
    float s = 0.f;
#pragma unroll
    for (int d = 0; d < 64; ++d) s += Qs[i][d] * Ks[j][d];
    s = s * 0.125f + biasM[(size_t)((g * H + h) << 10) + (i << 5) + j];

    float mx = s;
#pragma unroll
    for (int o = 16; o > 0; o >>= 1) mx = fmaxf(mx, __shfl_xor(mx, o));
    float p = __expf(s - mx);
    float sum = p;
#pragma unroll
    for (int o = 16; o > 0; o >>= 1) sum += __shfl_xor(sum, o);
    p /= sum;
    P[i][j] = p;
    __syncthreads();

    float o0 = 0.f, o1 = 0.f;
#pragma unroll
    for (int kk = 0; kk < 32; ++kk) {
        float pv = P[i][kk];
        o0 += pv * Vs[kk][j];
        o1 += pv * Vs[kk][j + 32];
    }
    size_t oa = (size_t)(g * 32 + i) * D + h * HD;
    AO16[oa + j]      = (_Float16)o0;
    AO16[oa + j + 32] = (_Float16)o1;
}

// ---------------------------------------------------------------------------
extern "C" void kernel_launch(void* const* d_in, const int* in_sizes, int n_in,
                              void* d_out, int out_size, void* d_ws, size_t ws_size,
                              hipStream_t stream)
{
    const float* nodes = (const float*)d_in[0];
    const float* edges = (const float*)d_in[1];
    const float* Wq    = (const float*)d_in[2];
    const float* bq    = (const float*)d_in[3];
    const float* Wk    = (const float*)d_in[4];
    const float* bk    = (const float*)d_in[5];
    const float* Wv    = (const float*)d_in[6];
    const float* bv    = (const float*)d_in[7];
    const float* Wo    = (const float*)d_in[8];
    const float* bo    = (const float*)d_in[9];
    const float* We    = (const float*)d_in[10];
    const float* be    = (const float*)d_in[11];
    const int* senders   = (const int*)d_in[13];
    const int* receivers = (const int*)d_in[14];

    // workspace layout
    char* ws = (char*)d_ws;
    float* Qb    = (float*)ws;                                   // 4 MB
    float* Kb    = Qb + (size_t)N_NODES * D;                     // 4 MB
    float* Vb    = Kb + (size_t)N_NODES * D;                     // 4 MB
    float* biasM = Vb + (size_t)N_NODES * D;                     // 2 MB
    _Float16* nA16 = (_Float16*)(biasM + (size_t)G * H * 1024);  // 2 MB
    _Float16* wT16 = nA16 + (size_t)N_NODES * D;                 // 2 MB (4x512x512)
    _Float16* AO16 = wT16 + (size_t)4 * D * D;                   // 2 MB

    // 1) prep: edge bias matrix + node cast + weight transpose/cast
    prep_kernel<<<G + 512 + 1024, 256, 0, stream>>>(
        nodes, Wq, Wk, Wv, Wo, edges, We, be, senders, receivers,
        nA16, wT16, biasM);

    // 2) QKV GEMM (z = 0/1/2)
    GemmArgs qkv;
    qkv.A = nA16;
    qkv.BT = wT16;
    qkv.bias[0] = bq; qkv.bias[1] = bk; qkv.bias[2] = bv;
    qkv.C = Qb;   // Qb,Kb,Vb contiguous
    gemm_f16_kernel<<<dim3(D / 64, N_NODES / 64, 3), 256, 0, stream>>>(qkv);

    // 3) attention
    attn_kernel<<<dim3(G, H), 1024, 0, stream>>>(Qb, Kb, Vb, biasM, AO16);

    // 4) output GEMM (Wo at slot 3: pass BT offset so z=0 hits Wo)
    GemmArgs og;
    og.A = AO16;
    og.BT = wT16 + (size_t)3 * D * D;
    og.bias[0] = bo; og.bias[1] = bo; og.bias[2] = bo;
    og.C = (float*)d_out;
    gemm_f16_kernel<<<dim3(D / 64, N_NODES / 64, 1), 256, 0, stream>>>(og);
}